// Round 3
// baseline (512.621 us; speedup 1.0000x reference)
//
#include <hip/hip_runtime.h>
#include <math.h>

// B=32, C=3, H=W=512, window 11, sigma 1.5, VALID conv -> 502x502
#define H 512
#define W 512
#define OUT_H 502
#define OUT_W 502
#define C1c 1.0e-4f   // (0.01*1)^2
#define C2c 9.0e-4f   // (0.03*1)^2

#define TH 67             // output rows per block
#define NR 77             // TH+10 input rows, multiple of 11 (phase-aligned)
#define NT 512            // one thread per column, full 512-col width

// Row-streaming SSIM, 1 output column per thread, 512-thread blocks:
//  - 55 phase accumulators + ~30 working regs fit in <=85 VGPR ->
//    __launch_bounds__(512,6) -> 3 blocks/CU; grid = 8*96 = 768 = exactly
//    3 blocks per CU, one fully-resident round, no tail.
//  - prefetch issued AFTER the barrier so the __syncthreads vmcnt-drain does
//    not expose global latency; loads complete under the h-pass FMAs.
//  - slot p gets its first post-flush write at phase p -> mul instead of
//    zero+fmac (no per-row accumulator zeroing).
//  - Gaussian weights in SGPRs via readfirstlane; row bookkeeping is SALU.
__global__ __launch_bounds__(NT, 6)
void ssim_kernel(const float* __restrict__ img1,
                 const float* __restrict__ img2,
                 float* __restrict__ out) {
    __shared__ float2 ring[2][1024];   // pow-2 stride (8 KB/slot); cols 0..521 used
    __shared__ float wsum[8];

    const int tid = threadIdx.x;

    // Gaussian weights (runtime expf to match reference), pinned to SGPR
    float g[11];
    {
        float s = 0.f;
#pragma unroll
        for (int i = 0; i < 11; ++i) {
            float d = (float)(i - 5);
            g[i] = expf(-d * d * (1.0f / 4.5f));
            s += g[i];
        }
        float inv = 1.0f / s;
#pragma unroll
        for (int i = 0; i < 11; ++i) {
            g[i] *= inv;
            g[i] = __uint_as_float(__builtin_amdgcn_readfirstlane(__float_as_uint(g[i])));
        }
    }

    const int oyb = blockIdx.x * TH;      // output rows owned: [oyb, oyb+TH)
    const int Y0  = min(oyb, H - NR);     // shift last block up; rows all in-bounds
    const int plane = blockIdx.y;         // b*3 + c
    const size_t pbase = (size_t)plane * (H * W);
    const float* __restrict__ p1 = img1 + pbase;
    const float* __restrict__ p2 = img2 + pbase;

    const bool colok = (tid < OUT_W);

    // zero the pad region once (cols 512..527 of both slots) so halo reads by
    // threads 502..511 (whose results are discarded) see defined data
    if (tid < 16) {
        ring[0][W + tid] = make_float2(0.f, 0.f);
        ring[1][W + tid] = make_float2(0.f, 0.f);
    }

    // 11 phase slots of vertical partial sums, 5 quantities
    float a0[11], a1[11], a2[11], a3[11], a4[11];
#pragma unroll
    for (int i = 0; i < 11; ++i) { a0[i]=0.f; a1[i]=0.f; a2[i]=0.f; a3[i]=0.f; a4[i]=0.f; }

    float lsum = 0.f;

    // byte-offset prefetch index; capped advance (no per-row y clamp math)
    int foff = (Y0 * W + tid) * 4;
    const int fcap = ((H - 1) * W + tid) * 4;
    float va = *(const float*)((const char*)p1 + foff);
    float vb = *(const float*)((const char*)p2 + foff);

#pragma unroll 1
    for (int rb = 0; rb < NR; rb += 11) {
#pragma unroll
        for (int p = 0; p < 11; ++p) {
            const int r = rb + p;
            const int slot = r & 1;

            // stage current row (consumes va/vb -> vmcnt drained here, not at barrier)
            ring[slot][tid] = make_float2(va, vb);

            __syncthreads();

            // issue next-row prefetch AFTER the barrier; latency hides under h-pass
            foff = min(foff + W * 4, fcap);
            va = *(const float*)((const char*)p1 + foff);
            vb = *(const float*)((const char*)p2 + foff);

            // horizontal 11-tap conv of the 5 quantities (products on the fly)
            float h0, h1, h2, h3, h4;
            {
                const float2* rp = &ring[slot][tid];
#pragma unroll
                for (int t = 0; t < 11; ++t) {
                    const float2 v = rp[t];        // ds_read_b64, offset t*8
                    const float w = g[t];
                    const float q2 = v.x * v.x, q3 = v.y * v.y, q4 = v.x * v.y;
                    if (t == 0) {
                        h0 = w * v.x; h1 = w * v.y; h2 = w * q2; h3 = w * q3; h4 = w * q4;
                    } else {
                        h0 = fmaf(w, v.x, h0); h1 = fmaf(w, v.y, h1);
                        h2 = fmaf(w, q2, h2);  h3 = fmaf(w, q3, h3);
                        h4 = fmaf(w, q4, h4);
                    }
                }
            }

            // vertical scatter: row r gives weight g[(p-a) mod 11] to slot a;
            // slot a==p was flushed last row -> first write is a mul (no zeroing)
#pragma unroll
            for (int a = 0; a < 11; ++a) {
                const float w = g[(p - a + 11) % 11];   // compile-time -> SGPR
                if (a == p) {
                    a0[a] = w * h0; a1[a] = w * h1; a2[a] = w * h2;
                    a3[a] = w * h3; a4[a] = w * h4;
                } else {
                    a0[a] = fmaf(w, h0, a0[a]); a1[a] = fmaf(w, h1, a1[a]);
                    a2[a] = fmaf(w, h2, a2[a]); a3[a] = fmaf(w, h3, a3[a]);
                    a4[a] = fmaf(w, h4, a4[a]);
                }
            }

            // output row oy = Y0 + r - 10 completes in slot e = (p+1)%11
            if (r >= 10) {
                const int e = (p + 1) % 11;
                const int oy = Y0 + r - 10;            // SALU (uniform)
                if (oy >= oyb) {                       // row ownership (de-dup last block)
                    const float m1 = a0[e], m2 = a1[e];
                    const float m1s = m1 * m1, m2s = m2 * m2, m12 = m1 * m2;
                    const float sig1  = a2[e] - m1s;
                    const float sig2  = a3[e] - m2s;
                    const float sig12 = a4[e] - m12;
                    const float num = (2.f * m12 + C1c) * (2.f * sig12 + C2c);
                    const float den = (m1s + m2s + C1c) * (sig1 + sig2 + C2c);
                    const float v = num * __builtin_amdgcn_rcpf(den);
                    if (colok) lsum += v;
                }
            }
        }
    }

    // block reduce + one atomic per block
#pragma unroll
    for (int off = 32; off > 0; off >>= 1) lsum += __shfl_down(lsum, off, 64);
    if ((tid & 63) == 0) wsum[tid >> 6] = lsum;
    __syncthreads();
    if (tid == 0) {
        const float inv_count = 1.0f / (3.0f * (float)OUT_H * (float)OUT_W);
        float total = 0.f;
#pragma unroll
        for (int wv = 0; wv < 8; ++wv) total += wsum[wv];
        atomicAdd(&out[plane / 3], total * inv_count);
    }
}

__global__ void zero_out(float* out, int n) {
    int i = threadIdx.x + blockIdx.x * blockDim.x;
    if (i < n) out[i] = 0.f;
}

extern "C" void kernel_launch(void* const* d_in, const int* in_sizes, int n_in,
                              void* d_out, int out_size, void* d_ws, size_t ws_size,
                              hipStream_t stream) {
    const float* img1 = (const float*)d_in[0];
    const float* img2 = (const float*)d_in[1];
    float* out = (float*)d_out;

    zero_out<<<1, 64, 0, stream>>>(out, out_size);

    const int nplanes = in_sizes[0] / (H * W);          // 96
    dim3 grid((OUT_H + TH - 1) / TH,                    // 8 row-tiles
              nplanes);                                 // 96 planes
    ssim_kernel<<<grid, NT, 0, stream>>>(img1, img2, out);
}

// Round 4
// 275.231 us; speedup vs baseline: 1.8625x; 1.8625x over previous
//
#include <hip/hip_runtime.h>
#include <math.h>

// B=32, C=3, H=W=512, window 11, sigma 1.5, VALID conv -> 502x502
#define H 512
#define W 512
#define OUT_H 502
#define OUT_W 502
#define C1c 1.0e-4f   // (0.01*1)^2
#define C2c 9.0e-4f   // (0.03*1)^2

#define TH 111            // output rows per block
#define NR 121            // TH+10 input rows = 11*11 (phase-exact)
#define NCOLS 256         // output columns per block (one per thread)
#define HALO 10
#define RING_W 266        // NCOLS + HALO staged columns

// Row-streaming SSIM, 1 output column per thread, 256-thread blocks.
//  - grid = 2 col-tiles x 5 row-tiles x 96 planes = 960 blocks; at
//    __launch_bounds__(256,4) -> 4 blocks/CU -> ALL blocks resident in one
//    round (capacity 1024), no sequential tail.
//  - cap stays at 128 VGPR: Round-3 showed caps near the natural allocation
//    (~85) force the 55 phase accumulators into scratch (600 MB/dispatch of
//    spill traffic). Round-0 proved this body fits in 64 VGPR under cap 128.
//  - prefetch issued AFTER the barrier: loads drain at the NEXT row's
//    ds_write, not at the barrier's vmcnt(0) -> latency hides under h-pass.
//  - row addressing is wave-uniform (SALU s_add/s_min); loads are
//    global_load v, v_col, s[rowbase].
//  - slot p gets its first post-flush write at phase p -> mul, no zeroing.
//  - Gaussian weights pinned to SGPR via readfirstlane.
__global__ __launch_bounds__(256, 4)
void ssim_kernel(const float* __restrict__ img1,
                 const float* __restrict__ img2,
                 float* __restrict__ out) {
    __shared__ float2 ring[2][RING_W];   // (img1,img2) pairs, cols 0..265 of tile
    __shared__ float wsum[4];

    const int tid = threadIdx.x;

    // Gaussian weights (runtime expf to match reference), pinned to SGPR
    float g[11];
    {
        float s = 0.f;
#pragma unroll
        for (int i = 0; i < 11; ++i) {
            float d = (float)(i - 5);
            g[i] = expf(-d * d * (1.0f / 4.5f));
            s += g[i];
        }
        float inv = 1.0f / s;
#pragma unroll
        for (int i = 0; i < 11; ++i) {
            g[i] *= inv;
            g[i] = __uint_as_float(__builtin_amdgcn_readfirstlane(__float_as_uint(g[i])));
        }
    }

    const int X0  = blockIdx.x * NCOLS;   // column tile origin (0 or 256)
    const int oyb = blockIdx.y * TH;      // output rows owned: [oyb, oyb+TH)
    const int Y0  = min(oyb, H - NR);     // shift last row-tile up; rows in-bounds
    const int plane = blockIdx.z;         // b*3 + c
    const size_t pbase = (size_t)plane * (H * W);
    const float* __restrict__ p1 = img1 + pbase;
    const float* __restrict__ p2 = img2 + pbase;

    const int gx = X0 + tid;                       // this thread's column (<512)
    const int hx = min(X0 + NCOLS + tid, W - 1);   // halo column (used if tid<10)
    const bool colok = (gx < OUT_W);

    // 11 phase slots of vertical partial sums, 5 quantities.
    // (zero-init only to avoid formal UB; every slot is mul-overwritten at
    //  phase p==slot before its first epilogue read)
    float a0[11], a1[11], a2[11], a3[11], a4[11];
#pragma unroll
    for (int i = 0; i < 11; ++i) { a0[i]=0.f; a1[i]=0.f; a2[i]=0.f; a3[i]=0.f; a4[i]=0.f; }

    float lsum = 0.f;

    // wave-uniform row offset (SALU); per-lane part of the address is just gx/hx
    int rowoff = Y0 * W;
    const int rowcap = (H - 1) * W;

    // prime prefetch (row Y0)
    float va, vb, ha = 0.f, hb = 0.f;
    {
        const float* row1 = p1 + rowoff;
        const float* row2 = p2 + rowoff;
        va = row1[gx]; vb = row2[gx];
        if (tid < HALO) { ha = row1[hx]; hb = row2[hx]; }
    }

#pragma unroll 1
    for (int rb = 0; rb < NR; rb += 11) {
#pragma unroll
        for (int p = 0; p < 11; ++p) {
            const int r = rb + p;
            float2* rs = ring[r & 1];

            // stage current row (consumes va/vb -> vmcnt drains here)
            rs[tid] = make_float2(va, vb);
            if (tid < HALO) rs[NCOLS + tid] = make_float2(ha, hb);

            __syncthreads();

            // issue next-row prefetch AFTER the barrier; hides under h-pass.
            // (last iteration re-reads a clamped in-bounds row; data unused)
            rowoff = min(rowoff + W, rowcap);
            {
                const float* row1 = p1 + rowoff;
                const float* row2 = p2 + rowoff;
                va = row1[gx]; vb = row2[gx];
                if (tid < HALO) { ha = row1[hx]; hb = row2[hx]; }
            }

            // horizontal 11-tap conv of the 5 quantities (products on the fly)
            float h0, h1, h2, h3, h4;
            {
                const float2* rp = rs + tid;
#pragma unroll
                for (int t = 0; t < 11; ++t) {
                    const float2 v = rp[t];        // ds_read_b64, offset t*8
                    const float w = g[t];
                    const float q2 = v.x * v.x, q3 = v.y * v.y, q4 = v.x * v.y;
                    if (t == 0) {
                        h0 = w * v.x; h1 = w * v.y; h2 = w * q2; h3 = w * q3; h4 = w * q4;
                    } else {
                        h0 = fmaf(w, v.x, h0); h1 = fmaf(w, v.y, h1);
                        h2 = fmaf(w, q2, h2);  h3 = fmaf(w, q3, h3);
                        h4 = fmaf(w, q4, h4);
                    }
                }
            }

            // vertical scatter: row r gives weight g[(p-a) mod 11] to slot a;
            // slot a==p was flushed last row -> first write is a mul
#pragma unroll
            for (int a = 0; a < 11; ++a) {
                const float w = g[(p - a + 11) % 11];   // compile-time -> SGPR
                if (a == p) {
                    a0[a] = w * h0; a1[a] = w * h1; a2[a] = w * h2;
                    a3[a] = w * h3; a4[a] = w * h4;
                } else {
                    a0[a] = fmaf(w, h0, a0[a]); a1[a] = fmaf(w, h1, a1[a]);
                    a2[a] = fmaf(w, h2, a2[a]); a3[a] = fmaf(w, h3, a3[a]);
                    a4[a] = fmaf(w, h4, a4[a]);
                }
            }

            // output row oy = Y0 + r - 10 completes in slot e = (p+1)%11
            if (r >= 10) {
                const int e = (p + 1) % 11;
                const int oy = Y0 + r - 10;            // uniform (SALU)
                if (oy >= oyb) {                       // ownership (de-dup last tile)
                    const float m1 = a0[e], m2 = a1[e];
                    const float m1s = m1 * m1, m2s = m2 * m2, m12 = m1 * m2;
                    const float sig1  = a2[e] - m1s;
                    const float sig2  = a3[e] - m2s;
                    const float sig12 = a4[e] - m12;
                    const float num = (2.f * m12 + C1c) * (2.f * sig12 + C2c);
                    const float den = (m1s + m2s + C1c) * (sig1 + sig2 + C2c);
                    const float v = num * __builtin_amdgcn_rcpf(den);
                    if (colok) lsum += v;
                }
            }
        }
    }

    // block reduce + one atomic per block
#pragma unroll
    for (int off = 32; off > 0; off >>= 1) lsum += __shfl_down(lsum, off, 64);
    if ((tid & 63) == 0) wsum[tid >> 6] = lsum;
    __syncthreads();
    if (tid == 0) {
        const float inv_count = 1.0f / (3.0f * (float)OUT_H * (float)OUT_W);
        const float total = (wsum[0] + wsum[1] + wsum[2] + wsum[3]) * inv_count;
        atomicAdd(&out[plane / 3], total);
    }
}

__global__ void zero_out(float* out, int n) {
    int i = threadIdx.x + blockIdx.x * blockDim.x;
    if (i < n) out[i] = 0.f;
}

extern "C" void kernel_launch(void* const* d_in, const int* in_sizes, int n_in,
                              void* d_out, int out_size, void* d_ws, size_t ws_size,
                              hipStream_t stream) {
    const float* img1 = (const float*)d_in[0];
    const float* img2 = (const float*)d_in[1];
    float* out = (float*)d_out;

    zero_out<<<1, 64, 0, stream>>>(out, out_size);

    const int nplanes = in_sizes[0] / (H * W);          // 96
    dim3 grid(W / NCOLS,                                // 2 col-tiles
              (OUT_H + TH - 1) / TH,                    // 5 row-tiles
              nplanes);                                 // 96 planes -> 960 blocks
    ssim_kernel<<<grid, 256, 0, stream>>>(img1, img2, out);
}